// Round 1
// baseline (158.185 us; speedup 1.0000x reference)
//
#include <hip/hip_runtime.h>
#include <hip/hip_bf16.h>

// Problem: TripletLoss. N=8192 points, D=256 fp32 features, int targets in [0,128).
// out[0] = mean(relu(dist_ap - dist_an + 0.3)), out[1] = mean(dist_an > dist_ap)
// where dist_ap = row-wise max of dist over same-class (incl. diagonal),
//       dist_an = row-wise min of dist over different-class,
//       dist    = sqrt(clip(sq[i]+sq[j]-2*dot(xi,xj), 1e-12)).
//
// Strategy: bf16 MFMA 128x128 tiles of the Gram matrix, fused epilogue doing
// masked max/min on clipped d2 (sqrt deferred to finish kernel; d2>=1e-12>0 so
// uint-bit ordering == float ordering -> atomicMax/Min on unsigned workspace).

#define N 8192
#define D 256
#define MARGIN 0.3f

typedef __bf16  bf16x8  __attribute__((ext_vector_type(8)));
typedef float   floatx4 __attribute__((ext_vector_type(4)));

// ---------------- Kernel A: bf16 cast + row sq-norms + workspace init --------
__global__ __launch_bounds__(256) void prep_kernel(
    const float* __restrict__ X, unsigned short* __restrict__ Xb,
    float* __restrict__ sq, unsigned* __restrict__ pmax, unsigned* __restrict__ nmin) {
  const int row = blockIdx.x;
  const int t = threadIdx.x;
  float v = X[row * D + t];
  __hip_bfloat16 h = __float2bfloat16(v);
  Xb[row * D + t] = *reinterpret_cast<unsigned short*>(&h);
  float s = v * v;
#pragma unroll
  for (int o = 32; o > 0; o >>= 1) s += __shfl_down(s, o);
  __shared__ float ps[4];
  if ((t & 63) == 0) ps[t >> 6] = s;
  __syncthreads();
  if (t == 0) {
    sq[row] = ps[0] + ps[1] + ps[2] + ps[3];
    pmax[row] = 0u;             // identity for max of d2 (d2 >= 1e-12 > 0)
    nmin[row] = 0x7F800000u;    // +inf
  }
}

// ---------------- Kernel B: 128x128 Gram tile + fused masked max/min ---------
__global__ __launch_bounds__(256) void tile_kernel(
    const unsigned short* __restrict__ Xb, const float* __restrict__ sq,
    const int* __restrict__ tgt, unsigned* __restrict__ pmax, unsigned* __restrict__ nmin) {
  const int rowBase = blockIdx.y * 128;
  const int colBase = blockIdx.x * 128;
  const int t = threadIdx.x;
  const int lane = t & 63;
  const int wave = t >> 6;
  const int wy = wave >> 1;       // wave row within 2x2 wave grid (64 rows each)
  const int wx = wave & 1;        // wave col (64 cols each)
  const int quad = lane >> 4;     // 0..3
  const int l15 = lane & 15;      // 0..15

  __shared__ __align__(16) unsigned short As[128 * 32];  // [row][k] row-major
  __shared__ __align__(16) unsigned short Bs[128 * 32];  // [col][k] row-major
  __shared__ float sqr[128], sqc[128];
  __shared__ int   tr[128], tc[128];
  __shared__ unsigned pmL[128], nmL[128];

  if (t < 128) {
    sqr[t] = sq[rowBase + t];
    tr[t]  = tgt[rowBase + t];
    pmL[t] = 0u;
  } else {
    int u = t - 128;
    sqc[u] = sq[colBase + u];
    tc[u]  = tgt[colBase + u];
    nmL[u] = 0x7F800000u;
  }

  floatx4 acc[4][4];
#pragma unroll
  for (int mi = 0; mi < 4; ++mi)
#pragma unroll
    for (int nj = 0; nj < 4; ++nj)
      acc[mi][nj] = (floatx4){0.f, 0.f, 0.f, 0.f};

  const unsigned short* Ag = Xb + (size_t)rowBase * D;
  const unsigned short* Bg = Xb + (size_t)colBase * D;

  for (int k0 = 0; k0 < D; k0 += 32) {
    // ---- stage A/B tiles (128 rows x 32 k, bf16) via 16B vector loads ----
#pragma unroll
    for (int it = 0; it < 2; ++it) {
      int l = t + it * 256;            // 0..511 chunk id, 16B each
      int i  = l >> 2;                 // row/col within tile
      int kk = (l & 3) << 3;           // k offset within 32 (8 bf16 per chunk)
      *reinterpret_cast<uint4*>(&As[l * 8]) =
          *reinterpret_cast<const uint4*>(Ag + i * D + k0 + kk);
      *reinterpret_cast<uint4*>(&Bs[l * 8]) =
          *reinterpret_cast<const uint4*>(Bg + i * D + k0 + kk);
    }
    __syncthreads();

    // ---- fragments + MFMA: A[m=l15][k=quad*8+j], B[n=l15][k=quad*8+j] ----
    bf16x8 a[4], b[4];
#pragma unroll
    for (int mi = 0; mi < 4; ++mi)
      a[mi] = *reinterpret_cast<const bf16x8*>(&As[(wy * 64 + mi * 16 + l15) * 32 + quad * 8]);
#pragma unroll
    for (int nj = 0; nj < 4; ++nj)
      b[nj] = *reinterpret_cast<const bf16x8*>(&Bs[(wx * 64 + nj * 16 + l15) * 32 + quad * 8]);
#pragma unroll
    for (int mi = 0; mi < 4; ++mi)
#pragma unroll
      for (int nj = 0; nj < 4; ++nj)
        acc[mi][nj] = __builtin_amdgcn_mfma_f32_16x16x32_bf16(a[mi], b[nj], acc[mi][nj], 0, 0, 0);
    __syncthreads();
  }

  // ---- epilogue: masked max/min on clipped d2, per-lane then quad-shuffle ----
  float sqc_l[4]; int tc_l[4];
#pragma unroll
  for (int nj = 0; nj < 4; ++nj) {
    int jl = wx * 64 + nj * 16 + l15;
    sqc_l[nj] = sqc[jl];
    tc_l[nj]  = tc[jl];
  }

  float pm[16], nm[16];
#pragma unroll
  for (int s = 0; s < 16; ++s) { pm[s] = 0.f; nm[s] = __builtin_huge_valf(); }

#pragma unroll
  for (int mi = 0; mi < 4; ++mi) {
#pragma unroll
    for (int r = 0; r < 4; ++r) {
      int il = wy * 64 + mi * 16 + quad * 4 + r;
      float si = sqr[il];
      int   ti = tr[il];
      int   s  = mi * 4 + r;
#pragma unroll
      for (int nj = 0; nj < 4; ++nj) {
        float d2 = fmaxf(si + sqc_l[nj] - 2.f * acc[mi][nj][r], 1e-12f);
        bool same = (ti == tc_l[nj]);
        pm[s] = same ? fmaxf(pm[s], d2) : pm[s];
        nm[s] = same ? nm[s] : fminf(nm[s], d2);
      }
    }
  }

  // reduce across the 16 lanes of each quad (they share the same 16 rows)
#pragma unroll
  for (int o = 1; o < 16; o <<= 1) {
#pragma unroll
    for (int s = 0; s < 16; ++s) {
      pm[s] = fmaxf(pm[s], __shfl_xor(pm[s], o));
      nm[s] = fminf(nm[s], __shfl_xor(nm[s], o));
    }
  }

  if (l15 == 0) {
#pragma unroll
    for (int mi = 0; mi < 4; ++mi)
#pragma unroll
      for (int r = 0; r < 4; ++r) {
        int il = wy * 64 + mi * 16 + quad * 4 + r;
        atomicMax(&pmL[il], __float_as_uint(pm[mi * 4 + r]));
        atomicMin(&nmL[il], __float_as_uint(nm[mi * 4 + r]));
      }
  }
  __syncthreads();

  if (t < 128) {
    atomicMax(&pmax[rowBase + t], pmL[t]);
    atomicMin(&nmin[rowBase + t], nmL[t]);
  }
}

// ---------------- Kernel C: final loss/prec over 8192 rows -------------------
__global__ __launch_bounds__(256) void finish_kernel(
    const unsigned* __restrict__ pmax, const unsigned* __restrict__ nmin,
    float* __restrict__ out) {
  const int t = threadIdx.x;
  float lsum = 0.f, psum = 0.f;
  for (int i = t; i < N; i += 256) {
    float ap = sqrtf(__uint_as_float(pmax[i]));
    float an = sqrtf(__uint_as_float(nmin[i]));
    lsum += fmaxf(ap - an + MARGIN, 0.f);
    psum += (an > ap) ? 1.f : 0.f;
  }
#pragma unroll
  for (int o = 32; o > 0; o >>= 1) {
    lsum += __shfl_down(lsum, o);
    psum += __shfl_down(psum, o);
  }
  __shared__ float ls[4], ps[4];
  if ((t & 63) == 0) { ls[t >> 6] = lsum; ps[t >> 6] = psum; }
  __syncthreads();
  if (t == 0) {
    out[0] = (ls[0] + ls[1] + ls[2] + ls[3]) / (float)N;
    out[1] = (ps[0] + ps[1] + ps[2] + ps[3]) / (float)N;
  }
}

extern "C" void kernel_launch(void* const* d_in, const int* in_sizes, int n_in,
                              void* d_out, int out_size, void* d_ws, size_t ws_size,
                              hipStream_t stream) {
  const float* X  = (const float*)d_in[0];
  const int* tgt  = (const int*)d_in[1];
  float* out      = (float*)d_out;

  char* ws = (char*)d_ws;
  unsigned short* Xb = (unsigned short*)ws;                    // 8192*256*2 = 4 MiB
  float*    sq   = (float*)(ws + 4194304);                     // 32 KiB
  unsigned* pmax = (unsigned*)(ws + 4194304 + 32768);          // 32 KiB
  unsigned* nmin = (unsigned*)(ws + 4194304 + 65536);          // 32 KiB

  prep_kernel<<<N, 256, 0, stream>>>(X, Xb, sq, pmax, nmin);
  dim3 grid(N / 128, N / 128);
  tile_kernel<<<grid, 256, 0, stream>>>(Xb, sq, tgt, pmax, nmin);
  finish_kernel<<<1, 256, 0, stream>>>(pmax, nmin, out);
}

// Round 2
// 155.899 us; speedup vs baseline: 1.0147x; 1.0147x over previous
//
#include <hip/hip_runtime.h>
#include <hip/hip_bf16.h>

// Problem: TripletLoss. N=8192 points, D=256 fp32 features, int targets in [0,128).
// out[0] = mean(relu(dist_ap - dist_an + 0.3)), out[1] = mean(dist_an > dist_ap)
// dist = sqrt(clip(sq[i]+sq[j]-2*dot(xi,xj), 1e-12)); ap = masked row max (same
// class), an = masked row min (diff class). sqrt deferred (monotone); d2>0 so
// uint-bit order == float order -> atomicMax/Min on unsigned workspace.
//
// R1: staging via __builtin_amdgcn_global_load_lds (16B), XOR-swizzled source
// mapping to kill ds_read bank conflicts (padding impossible with lds-DMA).

#define N 8192
#define D 256
#define MARGIN 0.3f

typedef __bf16  bf16x8  __attribute__((ext_vector_type(8)));
typedef float   floatx4 __attribute__((ext_vector_type(4)));

__device__ __forceinline__ void load_lds16(const void* g, void* s) {
  __builtin_amdgcn_global_load_lds(
      (const __attribute__((address_space(1))) void*)g,
      (__attribute__((address_space(3))) void*)s, 16, 0, 0);
}

// ---------------- Kernel A: bf16 cast + row sq-norms + workspace init --------
// 256 blocks x 256 threads; each wave handles 8 rows (64 lanes x float4 = 256).
__global__ __launch_bounds__(256) void prep_kernel(
    const float* __restrict__ X, unsigned short* __restrict__ Xb,
    float* __restrict__ sq, unsigned* __restrict__ pmax, unsigned* __restrict__ nmin) {
  const int t = threadIdx.x;
  const int lane = t & 63, wave = t >> 6;
  const int row0 = blockIdx.x * 32 + wave * 8;
#pragma unroll
  for (int r = 0; r < 8; ++r) {
    const int row = row0 + r;
    float4 v = *reinterpret_cast<const float4*>(X + (size_t)row * D + lane * 4);
    ushort4 h;
    {
      __hip_bfloat16 b0 = __float2bfloat16(v.x), b1 = __float2bfloat16(v.y);
      __hip_bfloat16 b2 = __float2bfloat16(v.z), b3 = __float2bfloat16(v.w);
      h.x = *reinterpret_cast<unsigned short*>(&b0);
      h.y = *reinterpret_cast<unsigned short*>(&b1);
      h.z = *reinterpret_cast<unsigned short*>(&b2);
      h.w = *reinterpret_cast<unsigned short*>(&b3);
    }
    *reinterpret_cast<ushort4*>(Xb + (size_t)row * D + lane * 4) = h;
    float s = v.x * v.x + v.y * v.y + v.z * v.z + v.w * v.w;
#pragma unroll
    for (int o = 32; o > 0; o >>= 1) s += __shfl_down(s, o);
    if (lane == 0) {
      sq[row] = s;
      pmax[row] = 0u;             // identity for max of d2 (d2 >= 1e-12 > 0)
      nmin[row] = 0x7F800000u;    // +inf
    }
  }
}

// ---------------- Kernel B: 128x128 Gram tile + fused masked max/min ---------
__global__ __launch_bounds__(256) void tile_kernel(
    const unsigned short* __restrict__ Xb, const float* __restrict__ sq,
    const int* __restrict__ tgt, unsigned* __restrict__ pmax, unsigned* __restrict__ nmin) {
  const int rowBase = blockIdx.y * 128;
  const int colBase = blockIdx.x * 128;
  const int t = threadIdx.x;
  const int lane = t & 63;
  const int wave = t >> 6;
  const int wy = wave >> 1;       // wave row within 2x2 wave grid (64 rows each)
  const int wx = wave & 1;        // wave col (64 cols each)
  const int quad = lane >> 4;     // 0..3
  const int l15 = lane & 15;      // 0..15

  // Swizzled tiles: LDS 16B-chunk position p holds global chunk
  // (row = p>>2, c = (p&3) ^ (row&3)).  8 KB each.
  __shared__ __align__(16) unsigned short As[128 * 32];
  __shared__ __align__(16) unsigned short Bs[128 * 32];
  __shared__ float sqr[128], sqc[128];
  __shared__ int   tr[128], tc[128];
  __shared__ unsigned pmL[128], nmL[128];

  if (t < 128) {
    sqr[t] = sq[rowBase + t];
    tr[t]  = tgt[rowBase + t];
    pmL[t] = 0u;
  } else {
    int u = t - 128;
    sqc[u] = sq[colBase + u];
    tc[u]  = tgt[colBase + u];
    nmL[u] = 0x7F800000u;
  }

  floatx4 acc[4][4];
#pragma unroll
  for (int mi = 0; mi < 4; ++mi)
#pragma unroll
    for (int nj = 0; nj < 4; ++nj)
      acc[mi][nj] = (floatx4){0.f, 0.f, 0.f, 0.f};

  const unsigned short* Ag = Xb + (size_t)rowBase * D;
  const unsigned short* Bg = Xb + (size_t)colBase * D;

  // Per-thread global element offsets for the two staging issues (k0 added in loop).
  int goff[2];
#pragma unroll
  for (int it = 0; it < 2; ++it) {
    int p = t + it * 256;
    int row = p >> 2;
    int c = (p & 3) ^ (row & 3);
    goff[it] = row * D + c * 8;
  }
  // Wave-uniform LDS byte bases (lane i lands at base + i*16).
  int lbase[2];
#pragma unroll
  for (int it = 0; it < 2; ++it) lbase[it] = (it * 256 + wave * 64) * 16;

  // k-invariant ds_read byte addresses for the swizzled fragments.
  int aAddr[4], bAddr[4];
#pragma unroll
  for (int mi = 0; mi < 4; ++mi) {
    int row = wy * 64 + mi * 16 + l15;
    aAddr[mi] = (row * 4 + (quad ^ (row & 3))) * 16;
  }
#pragma unroll
  for (int nj = 0; nj < 4; ++nj) {
    int row = wx * 64 + nj * 16 + l15;
    bAddr[nj] = (row * 4 + (quad ^ (row & 3))) * 16;
  }

  for (int k0 = 0; k0 < D; k0 += 32) {
#pragma unroll
    for (int it = 0; it < 2; ++it) {
      load_lds16(Ag + goff[it] + k0, (char*)As + lbase[it]);
      load_lds16(Bg + goff[it] + k0, (char*)Bs + lbase[it]);
    }
    __syncthreads();   // drains vmcnt (compiler emits full waitcnt before barrier)

    bf16x8 a[4], b[4];
#pragma unroll
    for (int mi = 0; mi < 4; ++mi)
      a[mi] = *reinterpret_cast<const bf16x8*>((const char*)As + aAddr[mi]);
#pragma unroll
    for (int nj = 0; nj < 4; ++nj)
      b[nj] = *reinterpret_cast<const bf16x8*>((const char*)Bs + bAddr[nj]);
#pragma unroll
    for (int mi = 0; mi < 4; ++mi)
#pragma unroll
      for (int nj = 0; nj < 4; ++nj)
        acc[mi][nj] = __builtin_amdgcn_mfma_f32_16x16x32_bf16(a[mi], b[nj], acc[mi][nj], 0, 0, 0);
    __syncthreads();
  }

  // ---- epilogue: masked max/min on clipped d2, per-lane then quad-shuffle ----
  float sqc_l[4]; int tc_l[4];
#pragma unroll
  for (int nj = 0; nj < 4; ++nj) {
    int jl = wx * 64 + nj * 16 + l15;
    sqc_l[nj] = sqc[jl];
    tc_l[nj]  = tc[jl];
  }

  float pm[16], nm[16];
#pragma unroll
  for (int s = 0; s < 16; ++s) { pm[s] = 0.f; nm[s] = __builtin_huge_valf(); }

#pragma unroll
  for (int mi = 0; mi < 4; ++mi) {
#pragma unroll
    for (int r = 0; r < 4; ++r) {
      int il = wy * 64 + mi * 16 + quad * 4 + r;
      float si = sqr[il];
      int   ti = tr[il];
      int   s  = mi * 4 + r;
#pragma unroll
      for (int nj = 0; nj < 4; ++nj) {
        float d2 = fmaxf(si + sqc_l[nj] - 2.f * acc[mi][nj][r], 1e-12f);
        bool same = (ti == tc_l[nj]);
        pm[s] = same ? fmaxf(pm[s], d2) : pm[s];
        nm[s] = same ? nm[s] : fminf(nm[s], d2);
      }
    }
  }

#pragma unroll
  for (int o = 1; o < 16; o <<= 1) {
#pragma unroll
    for (int s = 0; s < 16; ++s) {
      pm[s] = fmaxf(pm[s], __shfl_xor(pm[s], o));
      nm[s] = fminf(nm[s], __shfl_xor(nm[s], o));
    }
  }

  if (l15 == 0) {
#pragma unroll
    for (int mi = 0; mi < 4; ++mi)
#pragma unroll
      for (int r = 0; r < 4; ++r) {
        int il = wy * 64 + mi * 16 + quad * 4 + r;
        atomicMax(&pmL[il], __float_as_uint(pm[mi * 4 + r]));
        atomicMin(&nmL[il], __float_as_uint(nm[mi * 4 + r]));
      }
  }
  __syncthreads();

  if (t < 128) {
    atomicMax(&pmax[rowBase + t], pmL[t]);
    atomicMin(&nmin[rowBase + t], nmL[t]);
  }
}

// ---------------- Kernel C: final loss/prec over 8192 rows -------------------
__global__ __launch_bounds__(256) void finish_kernel(
    const unsigned* __restrict__ pmax, const unsigned* __restrict__ nmin,
    float* __restrict__ out) {
  const int t = threadIdx.x;
  float lsum = 0.f, psum = 0.f;
  for (int i = t; i < N; i += 256) {
    float ap = sqrtf(__uint_as_float(pmax[i]));
    float an = sqrtf(__uint_as_float(nmin[i]));
    lsum += fmaxf(ap - an + MARGIN, 0.f);
    psum += (an > ap) ? 1.f : 0.f;
  }
#pragma unroll
  for (int o = 32; o > 0; o >>= 1) {
    lsum += __shfl_down(lsum, o);
    psum += __shfl_down(psum, o);
  }
  __shared__ float ls[4], ps[4];
  if ((t & 63) == 0) { ls[t >> 6] = lsum; ps[t >> 6] = psum; }
  __syncthreads();
  if (t == 0) {
    out[0] = (ls[0] + ls[1] + ls[2] + ls[3]) / (float)N;
    out[1] = (ps[0] + ps[1] + ps[2] + ps[3]) / (float)N;
  }
}

extern "C" void kernel_launch(void* const* d_in, const int* in_sizes, int n_in,
                              void* d_out, int out_size, void* d_ws, size_t ws_size,
                              hipStream_t stream) {
  const float* X  = (const float*)d_in[0];
  const int* tgt  = (const int*)d_in[1];
  float* out      = (float*)d_out;

  char* ws = (char*)d_ws;
  unsigned short* Xb = (unsigned short*)ws;                    // 4 MiB
  float*    sq   = (float*)(ws + 4194304);                     // 32 KiB
  unsigned* pmax = (unsigned*)(ws + 4194304 + 32768);          // 32 KiB
  unsigned* nmin = (unsigned*)(ws + 4194304 + 65536);          // 32 KiB

  prep_kernel<<<256, 256, 0, stream>>>(X, Xb, sq, pmax, nmin);
  dim3 grid(N / 128, N / 128);
  tile_kernel<<<grid, 256, 0, stream>>>(Xb, sq, tgt, pmax, nmin);
  finish_kernel<<<1, 256, 0, stream>>>(pmax, nmin, out);
}

// Round 3
// 121.423 us; speedup vs baseline: 1.3028x; 1.2839x over previous
//
#include <hip/hip_runtime.h>
#include <hip/hip_bf16.h>

// TripletLoss, N=8192, D=256 fp32, targets in [0,128).
// out[0] = mean(relu(dist_ap - dist_an + 0.3)), out[1] = mean(dist_an > dist_ap)
// dist = sqrt(clip(sq_i + sq_j - 2 dot(xi,xj), 1e-12)). Row max over same-class
// (ap), row min over diff-class (an). sqrt deferred (monotone); d2 > 0 so
// uint-bit order == float order -> atomicMax/Min on unsigned.
//
// R2: SYMMETRY. Only lower-triangle 128x128 blocks (2080 of 4096); each tile
// feeds BOTH row-side (rowBase) and col-side (colBase) reductions. Diagonal
// blocks double-count harmlessly (max/min idempotent). Row reduction uses a
// halving butterfly (15 shuffles/array, result lands one-row-per-lane);
// col reduction is in-register over mi/r + 2 cross-quad shuffles.

#define N 8192
#define D 256
#define MARGIN 0.3f

typedef __bf16  bf16x8  __attribute__((ext_vector_type(8)));
typedef float   floatx4 __attribute__((ext_vector_type(4)));

__device__ __forceinline__ void load_lds16(const void* g, void* s) {
  __builtin_amdgcn_global_load_lds(
      (const __attribute__((address_space(1))) void*)g,
      (__attribute__((address_space(3))) void*)s, 16, 0, 0);
}

// ---------------- Kernel A: bf16 cast + row sq-norms + workspace init --------
// 1024 blocks x 256 threads; each wave handles 2 rows (64 lanes x float4).
__global__ __launch_bounds__(256) void prep_kernel(
    const float* __restrict__ X, unsigned short* __restrict__ Xb,
    float* __restrict__ sq, unsigned* __restrict__ pmax, unsigned* __restrict__ nmin) {
  const int t = threadIdx.x;
  const int lane = t & 63, wave = t >> 6;
  const int row0 = blockIdx.x * 8 + wave * 2;
#pragma unroll
  for (int r = 0; r < 2; ++r) {
    const int row = row0 + r;
    float4 v = *reinterpret_cast<const float4*>(X + (size_t)row * D + lane * 4);
    ushort4 h;
    {
      __hip_bfloat16 b0 = __float2bfloat16(v.x), b1 = __float2bfloat16(v.y);
      __hip_bfloat16 b2 = __float2bfloat16(v.z), b3 = __float2bfloat16(v.w);
      h.x = *reinterpret_cast<unsigned short*>(&b0);
      h.y = *reinterpret_cast<unsigned short*>(&b1);
      h.z = *reinterpret_cast<unsigned short*>(&b2);
      h.w = *reinterpret_cast<unsigned short*>(&b3);
    }
    *reinterpret_cast<ushort4*>(Xb + (size_t)row * D + lane * 4) = h;
    float s = v.x * v.x + v.y * v.y + v.z * v.z + v.w * v.w;
#pragma unroll
    for (int o = 32; o > 0; o >>= 1) s += __shfl_down(s, o);
    if (lane == 0) {
      sq[row] = s;
      pmax[row] = 0u;             // identity for max of d2 (d2 >= 1e-12 > 0)
      nmin[row] = 0x7F800000u;    // +inf
    }
  }
}

// ---------------- Kernel B: triangular 128x128 Gram tiles, 2-sided epilogue --
__global__ __launch_bounds__(256) void tile_kernel(
    const unsigned short* __restrict__ Xb, const float* __restrict__ sq,
    const int* __restrict__ tgt, unsigned* __restrict__ pmax, unsigned* __restrict__ nmin) {
  // decode lower-triangle pair: bi -> (by >= bx)
  const int bi = blockIdx.x;
  int by = (int)((sqrtf(8.0f * (float)bi + 1.0f) - 1.0f) * 0.5f);
  while ((by + 1) * (by + 2) / 2 <= bi) ++by;
  while (by * (by + 1) / 2 > bi) --by;
  const int bx = bi - by * (by + 1) / 2;
  const int rowBase = by * 128;
  const int colBase = bx * 128;

  const int t = threadIdx.x;
  const int lane = t & 63;
  const int wave = t >> 6;
  const int wy = wave >> 1;       // wave row within 2x2 wave grid (64 rows each)
  const int wx = wave & 1;        // wave col (64 cols each)
  const int quad = lane >> 4;     // 0..3
  const int l15 = lane & 15;      // 0..15

  // Swizzled tiles: LDS 16B-chunk position p holds global chunk
  // (row = p>>2, c = (p&3) ^ (row&3)).  8 KB each.
  __shared__ __align__(16) unsigned short As[128 * 32];
  __shared__ __align__(16) unsigned short Bs[128 * 32];
  __shared__ float sqr[128], sqc[128];
  __shared__ int   tr[128], tc[128];
  __shared__ unsigned pmL[128], nmL[128];    // row-side block merge
  __shared__ unsigned pmLc[128], nmLc[128];  // col-side block merge

  if (t < 128) {
    sqr[t] = sq[rowBase + t];
    tr[t]  = tgt[rowBase + t];
    pmL[t] = 0u;
    nmL[t] = 0x7F800000u;
  } else {
    int u = t - 128;
    sqc[u] = sq[colBase + u];
    tc[u]  = tgt[colBase + u];
    pmLc[u] = 0u;
    nmLc[u] = 0x7F800000u;
  }

  floatx4 acc[4][4];
#pragma unroll
  for (int mi = 0; mi < 4; ++mi)
#pragma unroll
    for (int nj = 0; nj < 4; ++nj)
      acc[mi][nj] = (floatx4){0.f, 0.f, 0.f, 0.f};

  const unsigned short* Ag = Xb + (size_t)rowBase * D;
  const unsigned short* Bg = Xb + (size_t)colBase * D;

  // Per-thread global element offsets for the two staging issues.
  int goff[2];
#pragma unroll
  for (int it = 0; it < 2; ++it) {
    int p = t + it * 256;
    int row = p >> 2;
    int c = (p & 3) ^ (row & 3);
    goff[it] = row * D + c * 8;
  }
  int lbase[2];
#pragma unroll
  for (int it = 0; it < 2; ++it) lbase[it] = (it * 256 + wave * 64) * 16;

  // k-invariant ds_read byte addresses (swizzled).
  int aAddr[4], bAddr[4];
#pragma unroll
  for (int mi = 0; mi < 4; ++mi) {
    int row = wy * 64 + mi * 16 + l15;
    aAddr[mi] = (row * 4 + (quad ^ (row & 3))) * 16;
  }
#pragma unroll
  for (int nj = 0; nj < 4; ++nj) {
    int row = wx * 64 + nj * 16 + l15;
    bAddr[nj] = (row * 4 + (quad ^ (row & 3))) * 16;
  }

  for (int k0 = 0; k0 < D; k0 += 32) {
#pragma unroll
    for (int it = 0; it < 2; ++it) {
      load_lds16(Ag + goff[it] + k0, (char*)As + lbase[it]);
      load_lds16(Bg + goff[it] + k0, (char*)Bs + lbase[it]);
    }
    __syncthreads();

    bf16x8 a[4], b[4];
#pragma unroll
    for (int mi = 0; mi < 4; ++mi)
      a[mi] = *reinterpret_cast<const bf16x8*>((const char*)As + aAddr[mi]);
#pragma unroll
    for (int nj = 0; nj < 4; ++nj)
      b[nj] = *reinterpret_cast<const bf16x8*>((const char*)Bs + bAddr[nj]);
#pragma unroll
    for (int mi = 0; mi < 4; ++mi)
#pragma unroll
      for (int nj = 0; nj < 4; ++nj)
        acc[mi][nj] = __builtin_amdgcn_mfma_f32_16x16x32_bf16(a[mi], b[nj], acc[mi][nj], 0, 0, 0);
    __syncthreads();
  }

  // ---- two-sided epilogue on clipped d2 ----
  float sqc_l[4]; int tc_l[4];
#pragma unroll
  for (int nj = 0; nj < 4; ++nj) {
    int jl = wx * 64 + nj * 16 + l15;
    sqc_l[nj] = sqc[jl];
    tc_l[nj]  = tc[jl];
  }

  float pm[16], nm[16];     // row partials: s = mi*4+r
  float cmP[4], cmN[4];     // col partials: per nj (col = wx*64+nj*16+l15)
#pragma unroll
  for (int s = 0; s < 16; ++s) { pm[s] = 0.f; nm[s] = __builtin_huge_valf(); }
#pragma unroll
  for (int nj = 0; nj < 4; ++nj) { cmP[nj] = 0.f; cmN[nj] = __builtin_huge_valf(); }

#pragma unroll
  for (int mi = 0; mi < 4; ++mi) {
#pragma unroll
    for (int r = 0; r < 4; ++r) {
      int il = wy * 64 + mi * 16 + quad * 4 + r;
      float si = sqr[il];
      int   ti = tr[il];
      int   s  = mi * 4 + r;
#pragma unroll
      for (int nj = 0; nj < 4; ++nj) {
        float d2 = fmaxf(fmaf(-2.f, acc[mi][nj][r], si + sqc_l[nj]), 1e-12f);
        bool same = (ti == tc_l[nj]);
        pm[s]   = same ? fmaxf(pm[s], d2)   : pm[s];
        nm[s]   = same ? nm[s]              : fminf(nm[s], d2);
        cmP[nj] = same ? fmaxf(cmP[nj], d2) : cmP[nj];
        cmN[nj] = same ? cmN[nj]            : fminf(cmN[nj], d2);
      }
    }
  }

  // Row-side halving butterfly across the 16 lanes of each quad group:
  // after step m, pm[j] (j<m) holds the partial for row-index bit pattern
  // following l15's bits; finally pm[0] is the full reduction for s = l15.
#pragma unroll
  for (int m = 8; m >= 1; m >>= 1) {
#pragma unroll
    for (int j = 0; j < m; ++j) {
      bool up = (l15 & m) != 0;
      float sp = up ? pm[j] : pm[j + m];
      float sn = up ? nm[j] : nm[j + m];
      float rp = __shfl_xor(sp, m);
      float rn = __shfl_xor(sn, m);
      float kp = up ? pm[j + m] : pm[j];
      float kn = up ? nm[j + m] : nm[j];
      pm[j] = fmaxf(kp, rp);
      nm[j] = fminf(kn, rn);
    }
  }
  {
    int rowIdx = wy * 64 + ((l15 >> 2) << 4) + (quad << 2) + (l15 & 3);
    atomicMax(&pmL[rowIdx], __float_as_uint(pm[0]));
    atomicMin(&nmL[rowIdx], __float_as_uint(nm[0]));
  }

  // Col-side: reduce across the 4 quads (lanes l15+16q share col group).
#pragma unroll
  for (int nj = 0; nj < 4; ++nj) {
    cmP[nj] = fmaxf(cmP[nj], __shfl_xor(cmP[nj], 16));
    cmP[nj] = fmaxf(cmP[nj], __shfl_xor(cmP[nj], 32));
    cmN[nj] = fminf(cmN[nj], __shfl_xor(cmN[nj], 16));
    cmN[nj] = fminf(cmN[nj], __shfl_xor(cmN[nj], 32));
  }
  {
    float vP = (quad == 0) ? cmP[0] : (quad == 1) ? cmP[1] : (quad == 2) ? cmP[2] : cmP[3];
    float vN = (quad == 0) ? cmN[0] : (quad == 1) ? cmN[1] : (quad == 2) ? cmN[2] : cmN[3];
    int colIdx = wx * 64 + quad * 16 + l15;
    atomicMax(&pmLc[colIdx], __float_as_uint(vP));
    atomicMin(&nmLc[colIdx], __float_as_uint(vN));
  }
  __syncthreads();

  if (t < 128) {
    atomicMax(&pmax[rowBase + t], pmL[t]);
    atomicMin(&nmin[rowBase + t], nmL[t]);
  } else {
    int u = t - 128;
    atomicMax(&pmax[colBase + u], pmLc[u]);
    atomicMin(&nmin[colBase + u], nmLc[u]);
  }
}

// ---------------- Kernel C: final loss/prec (32 blocks, atomicAdd) -----------
__global__ __launch_bounds__(256) void finish_kernel(
    const unsigned* __restrict__ pmax, const unsigned* __restrict__ nmin,
    float* __restrict__ out) {
  const int t = threadIdx.x;
  const int i = blockIdx.x * 256 + t;
  float ap = sqrtf(__uint_as_float(pmax[i]));
  float an = sqrtf(__uint_as_float(nmin[i]));
  float lsum = fmaxf(ap - an + MARGIN, 0.f);
  float psum = (an > ap) ? 1.f : 0.f;
#pragma unroll
  for (int o = 32; o > 0; o >>= 1) {
    lsum += __shfl_down(lsum, o);
    psum += __shfl_down(psum, o);
  }
  __shared__ float ls[4], ps[4];
  if ((t & 63) == 0) { ls[t >> 6] = lsum; ps[t >> 6] = psum; }
  __syncthreads();
  if (t == 0) {
    atomicAdd(&out[0], (ls[0] + ls[1] + ls[2] + ls[3]) * (1.0f / (float)N));
    atomicAdd(&out[1], (ps[0] + ps[1] + ps[2] + ps[3]) * (1.0f / (float)N));
  }
}

extern "C" void kernel_launch(void* const* d_in, const int* in_sizes, int n_in,
                              void* d_out, int out_size, void* d_ws, size_t ws_size,
                              hipStream_t stream) {
  const float* X  = (const float*)d_in[0];
  const int* tgt  = (const int*)d_in[1];
  float* out      = (float*)d_out;

  char* ws = (char*)d_ws;
  unsigned short* Xb = (unsigned short*)ws;                    // 4 MiB
  float*    sq   = (float*)(ws + 4194304);                     // 32 KiB
  unsigned* pmax = (unsigned*)(ws + 4194304 + 32768);          // 32 KiB
  unsigned* nmin = (unsigned*)(ws + 4194304 + 65536);          // 32 KiB

  hipMemsetAsync(d_out, 0, (size_t)out_size * sizeof(float), stream);
  prep_kernel<<<1024, 256, 0, stream>>>(X, Xb, sq, pmax, nmin);
  tile_kernel<<<2080, 256, 0, stream>>>(Xb, sq, tgt, pmax, nmin);
  finish_kernel<<<32, 256, 0, stream>>>(pmax, nmin, out);
}